// Round 23
// baseline (64.966 us; speedup 1.0000x reference)
//
#include <hip/hip_runtime.h>
#include <hip/hip_bf16.h>

#define D 512            // d_in == d_out == 512
#define NROWS 65536      // output rows
#define NBINS 256        // bins by row>>8
#define RPB 256          // rows per bin
#define P1B 1024         // nnz per phase-1 scatter block
#define SEGCAP 16        // per (blk,bin) segment capacity
#define MAXBLK1 512      // max phase-1 scatter blocks (nnz <= 524288)
#define RCAP 32          // per-row slot capacity (Poisson mean 8; P(>32)~1e-12)
#define OVFCAP 4096      // overflow spill capacity

typedef float f32x4 __attribute__((ext_vector_type(4)));

// ---------- phase 1 (R15 exact): transpose (blocks 0..255) + LDS-binned scatter ----------
__global__ __launch_bounds__(256) void k_phase1(const float* __restrict__ w,
                                                __hip_bfloat16* __restrict__ wt,
                                                const int* __restrict__ rows,
                                                const int* __restrict__ cols,
                                                const float* __restrict__ vals, int nnz, int nblk1,
                                                uint2* __restrict__ gBin, int* __restrict__ gBinCnt,
                                                int* __restrict__ ovf_cnt, uint4* __restrict__ ovf) {
    int b = blockIdx.x, t = threadIdx.x;
    if (b < 256) {                               // weight transpose -> bf16 wT
        __shared__ float tile[32][33];
        int bx = b & 15, by = b >> 4;
        int tx = t & 31, ty = t >> 5;            // 32 x 8
        for (int i = ty; i < 32; i += 8)
            tile[i][tx] = w[(by * 32 + i) * D + bx * 32 + tx];
        __syncthreads();
        for (int i = ty; i < 32; i += 8)
            wt[(bx * 32 + i) * D + by * 32 + tx] = __float2bfloat16(tile[tx][i]);
        return;
    }
    __shared__ int  binCnt[NBINS];
    __shared__ uint2 binBuf[NBINS][SEGCAP];      // 32 KB
    b -= 256;
    binCnt[t] = 0;
    __syncthreads();
    int base = b * P1B;
    int end = base + P1B; if (end > nnz) end = nnz;
    for (int i = base + t; i < end; i += 256) {  // coalesced COO read
        int r = rows[i], c = cols[i];
        unsigned vb = __float_as_uint(vals[i]);
        int bin = r >> 8;
        int pos = atomicAdd(&binCnt[bin], 1);    // LDS atomic
        if (pos < SEGCAP) {
            binBuf[bin][pos] = make_uint2(((unsigned)r << 9) | (unsigned)c, vb);
        } else {                                 // rare (ovf_cnt pre-zeroed by memset)
            int o = atomicAdd(ovf_cnt, 1);
            if (o < OVFCAP) ovf[o] = make_uint4((unsigned)r, (unsigned)c, vb, 0u);
        }
    }
    __syncthreads();
    for (int idx = t; idx < NBINS * SEGCAP; idx += 256) {
        int bin = idx >> 4, slot = idx & (SEGCAP - 1);
        int cnt = binCnt[bin]; if (cnt > SEGCAP) cnt = SEGCAP;
        if (slot < cnt)
            gBin[((size_t)b * NBINS + bin) * SEGCAP + slot] = binBuf[bin][slot];
        if (slot == 0) gBinCnt[b * NBINS + bin] = cnt;
    }
}

// ---------- k_csr: one-pass LDS cursor-scatter (R22 proven) -> coalesced bucket write ----------
__global__ __launch_bounds__(1024) void k_csr(const uint2* __restrict__ gBin,
                                              const int* __restrict__ gBinCnt, int nblk1,
                                              uint2* __restrict__ bucket,   // [NROWS][RCAP]
                                              int* __restrict__ cnt,        // [NROWS]
                                              int* __restrict__ ovf_cnt,
                                              uint4* __restrict__ ovf) {
    __shared__ int  segCnt[MAXBLK1];             // 2 KB
    __shared__ int  cursor[RPB];                 // 1 KB
    __shared__ uint2 rowBuf[RPB][RCAP];          // 64 KB
    int bin = blockIdx.x, t = threadIdx.x;
    if (t < MAXBLK1) segCnt[t] = (t < nblk1) ? gBinCnt[t * NBINS + bin] : 0;
    if (t < RPB) cursor[t] = 0;
    __syncthreads();
    for (int idx = t; idx < nblk1 * SEGCAP; idx += 1024) {
        int blk = idx >> 4, slot = idx & (SEGCAP - 1);
        if (slot < segCnt[blk]) {
            uint2 p = gBin[((size_t)blk * NBINS + bin) * SEGCAP + slot];
            int r = (int)(p.x >> 9) & (RPB - 1);
            int pos = atomicAdd(&cursor[r], 1);
            if (pos < RCAP) {
                rowBuf[r][pos] = make_uint2(p.x & 511u, p.y);
            } else {                             // P ~ 1e-12 per row
                int o = atomicAdd(ovf_cnt, 1);
                if (o < OVFCAP)
                    ovf[o] = make_uint4(p.x >> 9, p.x & 511u, p.y, 0u);
            }
        }
    }
    __syncthreads();
    // coalesced write-out: 64 KB contiguous per block (all slots; unused slots never read)
    uint2* bb = bucket + (size_t)bin * RPB * RCAP;
    for (int k = t; k < RPB * RCAP; k += 1024)
        bb[k] = ((const uint2*)rowBuf)[k];
    if (t < RPB) {
        int c = cursor[t]; if (c > RCAP) c = RCAP;
        cnt[bin * RPB + t] = c;
    }
}

// unpack one bf16x8 gather and accumulate
#define ACC8(wb, vv)                                   \
    do {                                               \
        f32x4 w0, w1;                                  \
        w0.x = __uint_as_float((wb).x << 16);          \
        w0.y = __uint_as_float((wb).x & 0xffff0000u);  \
        w0.z = __uint_as_float((wb).y << 16);          \
        w0.w = __uint_as_float((wb).y & 0xffff0000u);  \
        w1.x = __uint_as_float((wb).z << 16);          \
        w1.y = __uint_as_float((wb).z & 0xffff0000u);  \
        w1.z = __uint_as_float((wb).w << 16);          \
        w1.w = __uint_as_float((wb).w & 0xffff0000u);  \
        a0 += (vv) * w0;                               \
        a1 += (vv) * w1;                               \
    } while (0)

// ---------- main compute (R11 exact form): one wave per row; readlane; 4 gathers in flight ----------
__global__ __launch_bounds__(256) void k_spmm(const int* __restrict__ cnts,
                                              const uint2* __restrict__ bucket,
                                              const uint4* __restrict__ wt4,   // bf16 wT, 64 uint4/row
                                              const f32x4* __restrict__ bias4,
                                              f32x4* __restrict__ out,
                                              const int* __restrict__ ovf_cnt,
                                              const uint4* __restrict__ ovf) {
    int wid = (int)((blockIdx.x * blockDim.x + threadIdx.x) >> 6);
    int row = __builtin_amdgcn_readfirstlane(wid);
    int lane = threadIdx.x & 63;
    f32x4 a0 = bias4[lane * 2];
    f32x4 a1 = bias4[lane * 2 + 1];
    int cnt = cnts[row];
    int novf = *ovf_cnt;                 // uniformly ~0
    if (cnt > RCAP) cnt = RCAP;
    uint2 mypair = make_uint2(0u, 0u);
    if (lane < cnt) mypair = bucket[(size_t)row * RCAP + lane];
    int nb4 = (cnt + 3) >> 2;
    for (int b4 = 0; b4 < nb4; ++b4) {
        int s = b4 << 2;
        unsigned c0 = (unsigned)__builtin_amdgcn_readlane((int)mypair.x, s);
        unsigned c1 = (unsigned)__builtin_amdgcn_readlane((int)mypair.x, s + 1);
        unsigned c2 = (unsigned)__builtin_amdgcn_readlane((int)mypair.x, s + 2);
        unsigned c3 = (unsigned)__builtin_amdgcn_readlane((int)mypair.x, s + 3);
        float v0 = __uint_as_float((unsigned)__builtin_amdgcn_readlane((int)mypair.y, s));
        float v1 = __uint_as_float((unsigned)__builtin_amdgcn_readlane((int)mypair.y, s + 1));
        float v2 = __uint_as_float((unsigned)__builtin_amdgcn_readlane((int)mypair.y, s + 2));
        float v3 = __uint_as_float((unsigned)__builtin_amdgcn_readlane((int)mypair.y, s + 3));
        uint4 wb0 = wt4[(size_t)c0 * 64 + lane];       // 4 independent gathers in flight
        uint4 wb1 = wt4[(size_t)c1 * 64 + lane];
        uint4 wb2 = wt4[(size_t)c2 * 64 + lane];
        uint4 wb3 = wt4[(size_t)c3 * 64 + lane];
        ACC8(wb0, v0);
        ACC8(wb1, v1);
        ACC8(wb2, v2);
        ACC8(wb3, v3);
    }
    if (novf > 0) {                      // rare spill path
        if (novf > OVFCAP) novf = OVFCAP;
        for (int e = 0; e < novf; ++e) {
            uint4 p = ovf[e];
            if ((int)p.x == row) {
                float v = __uint_as_float(p.z);
                uint4 wb = wt4[(size_t)p.y * 64 + lane];
                ACC8(wb, v);
            }
        }
    }
    f32x4* op = out + (size_t)row * (D / 4);
    op[lane * 2]     = a0;
    op[lane * 2 + 1] = a1;
}

// ---------- fallback path (tiny workspace) ----------
__global__ void k_init_bias(const float* __restrict__ bias, float* __restrict__ out, int total) {
    int i = blockIdx.x * blockDim.x + threadIdx.x;
    if (i < total) out[i] = bias[i & (D - 1)];
}

__global__ void k_atomic_spmm(const int* __restrict__ rows, const int* __restrict__ cols,
                              const float* __restrict__ vals, int nnz,
                              const float* __restrict__ w, float* __restrict__ out) {
    int wid = (int)((blockIdx.x * blockDim.x + threadIdx.x) >> 6);
    if (wid >= nnz) return;
    int lane = threadIdx.x & 63;
    int r = rows[wid];
    int c = cols[wid];
    float v = vals[wid];
    float* op = out + (size_t)r * D + lane * 8;
#pragma unroll
    for (int k = 0; k < 8; ++k) {
        float wv = w[(size_t)(lane * 8 + k) * D + c];
        atomicAdd(&op[k], v * wv);
    }
}

extern "C" void kernel_launch(void* const* d_in, const int* in_sizes, int n_in,
                              void* d_out, int out_size, void* d_ws, size_t ws_size,
                              hipStream_t stream) {
    const int*   rows   = (const int*)d_in[0];
    const int*   cols   = (const int*)d_in[1];
    const float* vals   = (const float*)d_in[2];
    const float* weight = (const float*)d_in[3];
    const float* bias   = (const float*)d_in[4];
    float*       out    = (float*)d_out;
    const int nnz = in_sizes[0];
    const int nblk1 = (nnz + P1B - 1) / P1B;

    // workspace carve-out
    char* ws = (char*)d_ws;
    size_t off = 0;
    auto alloc = [&](size_t bytes) -> void* {
        off = (off + 255) & ~(size_t)255;
        void* p = ws + off;
        off += bytes;
        return p;
    };
    __hip_bfloat16* wT = (__hip_bfloat16*)alloc((size_t)D * D * sizeof(__hip_bfloat16)); // 512 KiB
    int*   ovf_cnt = (int*)  alloc(256);
    uint4* ovf     = (uint4*)alloc((size_t)OVFCAP * sizeof(uint4));                      // 64 KiB
    uint2* gBin    = (uint2*)alloc((size_t)MAXBLK1 * NBINS * SEGCAP * sizeof(uint2));    // 16 MiB
    int*   gBinCnt = (int*)  alloc((size_t)MAXBLK1 * NBINS * sizeof(int));               // 512 KiB
    uint2* bucket  = (uint2*)alloc((size_t)NROWS * RCAP * sizeof(uint2));                // 16 MiB
    int*   cnt     = (int*)  alloc((size_t)NROWS * sizeof(int));                         // 256 KiB
    const size_t need_full = off;

    if (need_full <= ws_size && nblk1 <= MAXBLK1) {
        // ---- 3 dispatches (+4B memset): measured-best components recombined ----
        hipMemsetAsync(ovf_cnt, 0, sizeof(int), stream);
        k_phase1<<<256 + nblk1, 256, 0, stream>>>(weight, wT, rows, cols, vals, nnz, nblk1,
                                                  gBin, gBinCnt, ovf_cnt, ovf);
        k_csr<<<NBINS, 1024, 0, stream>>>(gBin, gBinCnt, nblk1, bucket, cnt, ovf_cnt, ovf);
        k_spmm<<<NROWS / 4, 256, 0, stream>>>(cnt, bucket, (const uint4*)wT,
                                              (const f32x4*)bias, (f32x4*)out, ovf_cnt, ovf);
    } else {
        // ---- atomic fallback ----
        k_init_bias<<<(out_size + 255) / 256, 256, 0, stream>>>(bias, out, out_size);
        k_atomic_spmm<<<((size_t)nnz * 64 + 255) / 256, 256, 0, stream>>>(rows, cols, vals, nnz, weight, out);
    }
}